// Round 3
// baseline (1471.517 us; speedup 1.0000x reference)
//
#include <hip/hip_runtime.h>

#define BATCH 256
#define TSTEPS 2048
#define NDIM 64
#define DIN 6
#define ALPHA 0.2f
// sqrt(2 * 0.2 * 0.15^2)
#define NSCALE 0.09486832980505137f

// R7: R5's validated single-wave register-broadcast scan core, unchanged,
// plus two structural changes that do NOT touch the recurrence:
//
// 1. TLP: 32 blocks x 8 waves. Each wave owns one batch (b = blk*8 + wave),
//    runs the exact R5 code. 2 waves per SIMD: R5 was ~52% per-wave stall
//    (600 cyc/step vs ~290 cyc issue); a co-resident wave issues during
//    those stalls -> ~2x scan throughput. No cross-wave communication of
//    any kind (R6 proved per-step barriers cost ~900 cyc).
//
// 2. Fused output projection (kills the ~186 us second kernel + the 128 MB
//    states re-read): per step, lane i forms q_o = W_out[o][i]*s_i; one
//    shfl_xor(32) fold routes channel 0 to lanes 0-31 and channel 1 to
//    lanes 32-63; a 5-level butterfly (xor 1,2,4,8,16 — stays within each
//    half) finishes both sums. Results stashed 8-deep (static indices) and
//    burst-stored by lanes 0 and 32. The states trajectory is BIT-IDENTICAL
//    to the harness-validated R4/R5 kernels; only out's reduction order
//    differs (~1e-6, noise vs the 0.0625 tolerance).
__device__ __forceinline__ float rdlane(float v, int lane) {
    return __uint_as_float((unsigned)__builtin_amdgcn_readlane((int)__float_as_uint(v), lane));
}

__global__ __launch_bounds__(512, 2) void rnn_fused_kernel(
    const float* __restrict__ u,      // [B, T, DIN]
    const float* __restrict__ noise,  // [B, T, N]
    const float* __restrict__ W_rec,  // [N, N]
    const float* __restrict__ W_in,   // [N, DIN]
    const float* __restrict__ W_out,  // [2, N]
    float* __restrict__ states,       // [B, T, N]
    float* __restrict__ out)          // [B, T, 2]
{
    const int w = threadIdx.x >> 6;          // wave id 0..7
    const int j = threadIdx.x & 63;          // lane
    const int b = blockIdx.x * 8 + w;        // one batch per wave

    // W_rec row j -> registers (64 VGPRs)
    float4 w4[16];
    const float4* wr = reinterpret_cast<const float4*>(W_rec + j * NDIM);
#pragma unroll
    for (int i = 0; i < 16; ++i) w4[i] = wr[i];

    float win[DIN];
#pragma unroll
    for (int d = 0; d < DIN; ++d) win[d] = W_in[j * DIN + d];

    const float wo0 = W_out[j];          // out channel 0, element j
    const float wo1 = W_out[NDIM + j];   // out channel 1, element j

    const float* nb = noise + (size_t)b * TSTEPS * NDIM;
    const float4* ub4 = reinterpret_cast<const float4*>(u + (size_t)b * TSTEPS * DIN);
    float* st = states + (size_t)b * TSTEPS * NDIM;
    float* ob = out + (size_t)b * TSTEPS * 2;

    float s = 0.0f;
    st[j] = 0.0f;  // states[b, 0, :] = 0
    if (j == 0) reinterpret_cast<float2*>(ob)[0] = make_float2(0.0f, 0.0f);

    float prb[8];  // projection stash (statically indexed only)

    // One recurrence step — identical arithmetic to the validated R5 kernel
    // (ax/ay/az/aw over column classes i%4, same order, same combine/blend).
    auto step_body = [&](int t, float nvk, const float* uuf, int k8) {
        float ax = 0.0f, ay = 0.0f, az = 0.0f, aw = 0.0f;
#pragma unroll
        for (int i = 0; i < 16; ++i) {
            const float4 wv = w4[i];
            const float sx = rdlane(s, 4 * i + 0);
            const float sy = rdlane(s, 4 * i + 1);
            const float sz = rdlane(s, 4 * i + 2);
            const float sw = rdlane(s, 4 * i + 3);
            ax = fmaf(wv.x, sx, ax);
            ay = fmaf(wv.y, sy, ay);
            az = fmaf(wv.z, sz, az);
            aw = fmaf(wv.w, sw, aw);
        }
        float d = NSCALE * nvk;
#pragma unroll
        for (int kk = 0; kk < DIN; ++kk) d = fmaf(win[kk], uuf[kk], d);

        const float acc = ((ax + ay) + (az + aw)) + d;
        s = fmaf(1.0f - ALPHA, s, ALPHA * fmaxf(acc, 0.0f));

        st[(size_t)(t + 1) * NDIM + j] = s;  // fire-and-forget

        // Fused projection: q_o = W_out[o][j]*s_j; fold halves, butterfly.
        const float q0 = wo0 * s;
        const float q1 = wo1 * s;
        const float t0 = __shfl_xor(q0, 32);
        const float t1 = __shfl_xor(q1, 32);
        float r = (j & 32) ? (q1 + t1) : (q0 + t0);
        r += __shfl_xor(r, 1);
        r += __shfl_xor(r, 2);
        r += __shfl_xor(r, 4);
        r += __shfl_xor(r, 8);
        r += __shfl_xor(r, 16);
        prb[k8] = r;  // lanes 0-31: p0(t+1); lanes 32-63: p1(t+1)
    };

    // Prefetch buffers: 8 steps of noise (per-lane dword) and u (wave-uniform,
    // 12 float4). A/B ping-pong, guard-free.
    float nva[8], nvb[8];
    float4 uua[12], uub[12];
#pragma unroll
    for (int k = 0; k < 8; ++k) nva[k] = nb[k * NDIM + j];
#pragma unroll
    for (int k = 0; k < 12; ++k) uua[k] = ub4[k];

    // 8 guard-free steps from (nv,uu) while prefetching tb+8..tb+15 into
    // (nvN,uuN); then burst-store the 8 stashed projections.
    auto run8 = [&](int tb, const float* nv, const float4* uu,
                    float* nvN, float4* uuN) {
        const int tpf = tb + 8;
#pragma unroll
        for (int k = 0; k < 8; ++k) nvN[k] = nb[(tpf + k) * NDIM + j];
        const int ubase = tpf * DIN / 4;  // tpf multiple of 8 -> exact
#pragma unroll
        for (int k = 0; k < 12; ++k) uuN[k] = ub4[ubase + k];

        const float* uuf = reinterpret_cast<const float*>(uu);
#pragma unroll
        for (int k = 0; k < 8; ++k) step_body(tb + k, nv[k], uuf + k * DIN, k);

        if ((j & 31) == 0) {
            const int o = j >> 5;
#pragma unroll
            for (int k = 0; k < 8; ++k)
                ob[(size_t)(tb + 1 + k) * 2 + o] = prb[k];
        }
    };

    // T-1 = 2047 steps: 127*16 (ping-pong pairs) + 8 + 7-step tail.
    int tb = 0;
    for (int it = 0; it < 127; ++it) {
        run8(tb, nva, uua, nvb, uub); tb += 8;   // uses A, refills B
        run8(tb, nvb, uub, nva, uua); tb += 8;   // uses B, refills A
    }
    // tb == 2032; A holds 2032..2039. Prefetch 2040..2047 into B (in-bounds).
    run8(2032, nva, uua, nvb, uub);
    // Tail: steps 2040..2046 (7 steps) from B, no further prefetch.
    {
        const float* uuf = reinterpret_cast<const float*>(uub);
#pragma unroll
        for (int k = 0; k < 7; ++k) step_body(2040 + k, nvb[k], uuf + k * DIN, k);
        if ((j & 31) == 0) {
            const int o = j >> 5;
#pragma unroll
            for (int k = 0; k < 7; ++k)
                ob[(size_t)(2041 + k) * 2 + o] = prb[k];
        }
    }
}

extern "C" void kernel_launch(void* const* d_in, const int* in_sizes, int n_in,
                              void* d_out, int out_size, void* d_ws, size_t ws_size,
                              hipStream_t stream) {
    const float* u     = (const float*)d_in[0];
    const float* noise = (const float*)d_in[1];
    const float* W_rec = (const float*)d_in[2];
    const float* W_in  = (const float*)d_in[3];
    const float* W_out = (const float*)d_in[4];

    float* states = (float*)d_out;                           // B*T*N floats
    float* out    = states + (size_t)BATCH * TSTEPS * NDIM;  // B*T*2 floats

    rnn_fused_kernel<<<32, 512, 0, stream>>>(u, noise, W_rec, W_in, W_out,
                                             states, out);
}

// Round 4
// 712.868 us; speedup vs baseline: 2.0642x; 2.0642x over previous
//
#include <hip/hip_runtime.h>

#define BATCH 256
#define TSTEPS 2048
#define NDIM 64
#define DIN 6
#define ALPHA 0.2f
// sqrt(2 * 0.2 * 0.15^2)
#define NSCALE 0.09486832980505137f

typedef float f32x2 __attribute__((ext_vector_type(2)));

// R8: single wave per batch per CU (the only viable topology — R6 proved
// per-step cross-wave sync costs ~900 cyc; R7 proved multi-chain-per-CU
// only dilutes issue slots). Per-step cost attacked on both terms:
//
//   transport: HYBRID broadcast. Elements 0-15 via v_readlane (register
//   path, issues immediately, covers LDS latency); elements 16-63 via 12
//   uniform-address ds_read_b128 broadcasts issued right after sb[j]=s, so
//   the ~120 cyc LDS round-trip hides under the readlane/fma block.
//   Single-wave in-order LDS pipe makes write->read ordering hardware-
//   correct with no barrier (R4-validated pattern); wave_barrier pins the
//   compiler schedule.
//
//   issue count: v_pk_fma_f32. The b128 quads land in aligned VGPR pairs;
//   float2 __builtin_elementwise_fma maps to packed fma, halving the
//   LDS-side matvec (24 pk_fma instead of 48 fma). ~145 -> ~80 VALU/step.
//
// Numerics: BIT-IDENTICAL to the validated R4/R5 kernels. Chains ax/ay/az/aw
// take the same terms in the same order (scalar i=0..3, packed i=4..15;
// pk_fma = two independent IEEE fmas); drive/combine/blend unchanged.
__device__ __forceinline__ float rdlane(float v, int lane) {
    return __uint_as_float((unsigned)__builtin_amdgcn_readlane((int)__float_as_uint(v), lane));
}

__global__ __launch_bounds__(64, 1) void rnn_scan_kernel(
    const float* __restrict__ u,      // [B, T, DIN]
    const float* __restrict__ noise,  // [B, T, N]
    const float* __restrict__ W_rec,  // [N, N]
    const float* __restrict__ W_in,   // [N, DIN]
    float* __restrict__ states)       // [B, T, N]
{
    const int b = blockIdx.x;
    const int j = threadIdx.x;

    __shared__ float sb[NDIM];

    // W_rec row j -> registers (64 VGPRs). Scalar quads for i=0..3,
    // packed pairs for i=4..15 (same data, aliased pairs are free).
    float4 w4[4];
    f32x2 wA[12], wB[12];
    const float4* wr = reinterpret_cast<const float4*>(W_rec + j * NDIM);
#pragma unroll
    for (int i = 0; i < 4; ++i) w4[i] = wr[i];
#pragma unroll
    for (int i = 0; i < 12; ++i) {
        const float4 wv = wr[4 + i];
        wA[i] = f32x2{wv.x, wv.y};
        wB[i] = f32x2{wv.z, wv.w};
    }

    float win[DIN];
#pragma unroll
    for (int d = 0; d < DIN; ++d) win[d] = W_in[j * DIN + d];

    const float* nb = noise + (size_t)b * TSTEPS * NDIM;
    const float4* ub4 = reinterpret_cast<const float4*>(u + (size_t)b * TSTEPS * DIN);
    float* st = states + (size_t)b * TSTEPS * NDIM;

    float s = 0.0f;
    st[j] = 0.0f;  // states[b, 0, :] = 0

    auto step_body = [&](int t, float nvk, const float* uuf) {
        // Publish s; uniform b128 broadcast reads for elements 16..63 issue
        // first so their latency hides under the readlane block below.
        sb[j] = s;
        __builtin_amdgcn_wave_barrier();
        f32x2 spA[12], spB[12];
#pragma unroll
        for (int i = 0; i < 12; ++i) {
            const float4 sv = reinterpret_cast<const float4*>(sb)[4 + i];
            spA[i] = f32x2{sv.x, sv.y};
            spB[i] = f32x2{sv.z, sv.w};
        }

        // Elements 0..15 via readlane — identical ops/order to validated
        // kernel's first 4 float4 groups.
        float ax = 0.0f, ay = 0.0f, az = 0.0f, aw = 0.0f;
#pragma unroll
        for (int i = 0; i < 4; ++i) {
            const float4 wv = w4[i];
            const float sx = rdlane(s, 4 * i + 0);
            const float sy = rdlane(s, 4 * i + 1);
            const float sz = rdlane(s, 4 * i + 2);
            const float sw = rdlane(s, 4 * i + 3);
            ax = fmaf(wv.x, sx, ax);
            ay = fmaf(wv.y, sy, ay);
            az = fmaf(wv.z, sz, az);
            aw = fmaf(wv.w, sw, aw);
        }
        // Elements 16..63: packed fma continues the same four chains.
        f32x2 accA = {ax, ay};
        f32x2 accB = {az, aw};
#pragma unroll
        for (int i = 0; i < 12; ++i) {
            accA = __builtin_elementwise_fma(wA[i], spA[i], accA);
            accB = __builtin_elementwise_fma(wB[i], spB[i], accB);
        }

        // Drive (identical to validated kernel)
        float d = NSCALE * nvk;
#pragma unroll
        for (int kk = 0; kk < DIN; ++kk) d = fmaf(win[kk], uuf[kk], d);

        const float acc = ((accA.x + accA.y) + (accB.x + accB.y)) + d;
        s = fmaf(1.0f - ALPHA, s, ALPHA * fmaxf(acc, 0.0f));

        st[(size_t)(t + 1) * NDIM + j] = s;  // fire-and-forget
    };

    // Prefetch buffers: 8 steps of noise (per-lane dword) and u (wave-uniform,
    // 12 float4). A/B ping-pong, guard-free.
    float nva[8], nvb[8];
    float4 uua[12], uub[12];
#pragma unroll
    for (int k = 0; k < 8; ++k) nva[k] = nb[k * NDIM + j];
#pragma unroll
    for (int k = 0; k < 12; ++k) uua[k] = ub4[k];

    auto run8 = [&](int tb, const float* nv, const float4* uu,
                    float* nvN, float4* uuN) {
        const int tpf = tb + 8;
#pragma unroll
        for (int k = 0; k < 8; ++k) nvN[k] = nb[(tpf + k) * NDIM + j];
        const int ubase = tpf * DIN / 4;  // tpf multiple of 8 -> exact
#pragma unroll
        for (int k = 0; k < 12; ++k) uuN[k] = ub4[ubase + k];

        const float* uuf = reinterpret_cast<const float*>(uu);
#pragma unroll
        for (int k = 0; k < 8; ++k) step_body(tb + k, nv[k], uuf + k * DIN);
    };

    // T-1 = 2047 steps: 127*16 (ping-pong pairs) + 8 + 7-step tail.
    int tb = 0;
    for (int it = 0; it < 127; ++it) {
        run8(tb, nva, uua, nvb, uub); tb += 8;   // uses A, refills B
        run8(tb, nvb, uub, nva, uua); tb += 8;   // uses B, refills A
    }
    // tb == 2032; A holds 2032..2039. Prefetch 2040..2047 into B (in-bounds).
    run8(2032, nva, uua, nvb, uub);
    // Tail: steps 2040..2046 (7 steps) from B, no further prefetch.
    {
        const float* uuf = reinterpret_cast<const float*>(uub);
#pragma unroll
        for (int k = 0; k < 7; ++k) step_body(2040 + k, nvb[k], uuf + k * DIN);
    }
}

// out[r, o] = sum_n states[r, n] * W_out[o][n]. Quad scheme (validated):
// 4 lanes per row, 16 contiguous floats per lane, wave covers 16 rows = 4 KB
// contiguous. ~25 us at this grid; the remaining bench gap is fixed harness
// overhead (~160 us), proven by R6/R7 single-kernel runs.
__global__ __launch_bounds__(256) void out_proj_kernel(
    const float* __restrict__ states,  // [B*T, N]
    const float* __restrict__ W_out,   // [2, N]
    float* __restrict__ out)           // [B*T, 2]
{
    const int lane = threadIdx.x & 63;
    const int seg = lane & 3;    // which 16-elem segment of the row
    const int rsub = lane >> 2;  // row within the 16-row group

    const size_t wave = (size_t)(blockIdx.x * blockDim.x + threadIdx.x) >> 6;
    const size_t nwaves = ((size_t)gridDim.x * blockDim.x) >> 6;
    const size_t ngroups = (size_t)BATCH * TSTEPS / 16;

    float4 w0[4], w1[4];
    const float4* wo = reinterpret_cast<const float4*>(W_out);
#pragma unroll
    for (int i = 0; i < 4; ++i) {
        w0[i] = wo[seg * 4 + i];       // W_out[0][seg*16 + i*4 ..]
        w1[i] = wo[16 + seg * 4 + i];  // W_out[1][seg*16 + i*4 ..]
    }

    for (size_t g = wave; g < ngroups; g += nwaves) {
        const size_t r = g * 16 + rsub;
        const float4* sp = reinterpret_cast<const float4*>(states + r * NDIM + seg * 16);
        float p0 = 0.0f, p1 = 0.0f;
#pragma unroll
        for (int i = 0; i < 4; ++i) {
            const float4 sv = sp[i];
            p0 = fmaf(sv.x, w0[i].x, p0); p0 = fmaf(sv.y, w0[i].y, p0);
            p0 = fmaf(sv.z, w0[i].z, p0); p0 = fmaf(sv.w, w0[i].w, p0);
            p1 = fmaf(sv.x, w1[i].x, p1); p1 = fmaf(sv.y, w1[i].y, p1);
            p1 = fmaf(sv.z, w1[i].z, p1); p1 = fmaf(sv.w, w1[i].w, p1);
        }
        p0 += __shfl_xor(p0, 1); p0 += __shfl_xor(p0, 2);
        p1 += __shfl_xor(p1, 1); p1 += __shfl_xor(p1, 2);
        if (seg == 0) {
            reinterpret_cast<float2*>(out)[r] = make_float2(p0, p1);
        }
    }
}

extern "C" void kernel_launch(void* const* d_in, const int* in_sizes, int n_in,
                              void* d_out, int out_size, void* d_ws, size_t ws_size,
                              hipStream_t stream) {
    const float* u     = (const float*)d_in[0];
    const float* noise = (const float*)d_in[1];
    const float* W_rec = (const float*)d_in[2];
    const float* W_in  = (const float*)d_in[3];
    const float* W_out = (const float*)d_in[4];

    float* states = (float*)d_out;                           // B*T*N floats
    float* out    = states + (size_t)BATCH * TSTEPS * NDIM;  // B*T*2 floats

    rnn_scan_kernel<<<BATCH, 64, 0, stream>>>(u, noise, W_rec, W_in, states);
    out_proj_kernel<<<2048, 256, 0, stream>>>(states, W_out, out);
}